// Round 1
// baseline (2043.661 us; speedup 1.0000x reference)
//
#include <hip/hip_runtime.h>
#include <hip/hip_bf16.h>
#include <math.h>

// ---------- types ----------
typedef __attribute__((ext_vector_type(4))) float  float4v;
typedef __attribute__((ext_vector_type(8))) unsigned short ushort8v;
typedef __attribute__((ext_vector_type(4))) unsigned short ushort4v;
typedef __attribute__((ext_vector_type(8))) __bf16 bf16x8;

#define BB   8192
#define NN   4
#define DD   2048
#define ND   8192   // N*D
#define DFF  8192
#define EPSF 1.1920928955078125e-07f

__device__ __forceinline__ unsigned short f2bf(float f) {
  union { float f; unsigned int u; } v; v.f = f;
  unsigned int u = v.u;
  u += 0x7FFFu + ((u >> 16) & 1u);   // round-to-nearest-even
  return (unsigned short)(u >> 16);
}

// ---------------------------------------------------------------------------
// Kernel 1: per-row RMS stats + xn@theta_{pre,post,res} + sigmoid + sinkhorn
// One block (256 threads) per row b. Single pass over x: accumulate sumsq of
// raw x and 24 dot products of (x*w) with theta rows; apply rms scale after.
// ---------------------------------------------------------------------------
__global__ __launch_bounds__(256) void row_stats_kernel(
    const float* __restrict__ x, const float* __restrict__ w,
    const float* __restrict__ th_pre, const float* __restrict__ th_post,
    const float* __restrict__ th_res,
    const float* __restrict__ a_pre, const float* __restrict__ a_post,
    const float* __restrict__ a_res,
    const float* __restrict__ b_pre, const float* __restrict__ b_post,
    const float* __restrict__ b_res,
    float* __restrict__ Hpre, float* __restrict__ Hpost, float* __restrict__ Hres)
{
  const int b = blockIdx.x;
  const int t = threadIdx.x;
  const float* xr = x + (size_t)b * ND;

  float acc[25];   // [0]=sumsq, [1..4]=pre, [5..8]=post, [9..24]=res
#pragma unroll
  for (int v = 0; v < 25; ++v) acc[v] = 0.0f;

  const float4v* tp = (const float4v*)th_pre;   // row i -> tp[i]
  const float4v* tq = (const float4v*)th_post;
  const float4v* tr = (const float4v*)th_res;   // row i -> tr[i*4 .. i*4+3]

  for (int j = 0; j < ND / 256; ++j) {
    int i = j * 256 + t;
    float xv = xr[i];
    float xw = xv * w[i];
    acc[0] += xv * xv;
    float4v p = tp[i];
    acc[1] += xw * p.x; acc[2] += xw * p.y; acc[3] += xw * p.z; acc[4] += xw * p.w;
    float4v q = tq[i];
    acc[5] += xw * q.x; acc[6] += xw * q.y; acc[7] += xw * q.z; acc[8] += xw * q.w;
#pragma unroll
    for (int r = 0; r < 4; ++r) {
      float4v rv = tr[i * 4 + r];
      acc[9 + r * 4 + 0] += xw * rv.x;
      acc[9 + r * 4 + 1] += xw * rv.y;
      acc[9 + r * 4 + 2] += xw * rv.z;
      acc[9 + r * 4 + 3] += xw * rv.w;
    }
  }

  // wave (64-lane) shuffle reduction
#pragma unroll
  for (int v = 0; v < 25; ++v) {
#pragma unroll
    for (int off = 32; off > 0; off >>= 1)
      acc[v] += __shfl_down(acc[v], off);
  }

  __shared__ float red[4][25];
  int lane = t & 63, wv = t >> 6;
  if (lane == 0) {
#pragma unroll
    for (int v = 0; v < 25; ++v) red[wv][v] = acc[v];
  }
  __syncthreads();

  if (t == 0) {
    float s[25];
#pragma unroll
    for (int v = 0; v < 25; ++v)
      s[v] = red[0][v] + red[1][v] + red[2][v] + red[3][v];

    float scale = rsqrtf(s[0] / (float)ND + EPSF);
    float ap = a_pre[0], apo = a_post[0], ar = a_res[0];

#pragma unroll
    for (int n = 0; n < 4; ++n) {
      float vpre = ap * s[1 + n] * scale + b_pre[n];
      Hpre[b * 4 + n] = 1.0f / (1.0f + expf(-vpre));
      float vpost = apo * s[5 + n] * scale + b_post[n];
      Hpost[b * 4 + n] = 2.0f / (1.0f + expf(-vpost));
    }

    float m[16];
#pragma unroll
    for (int k = 0; k < 16; ++k)
      m[k] = expf(ar * s[9 + k] * scale + b_res[k]);

    for (int it = 0; it < 20; ++it) {
#pragma unroll
      for (int n = 0; n < 4; ++n) {
        float rs = m[n*4] + m[n*4+1] + m[n*4+2] + m[n*4+3];
        float inv = 1.0f / rs;
        m[n*4] *= inv; m[n*4+1] *= inv; m[n*4+2] *= inv; m[n*4+3] *= inv;
      }
#pragma unroll
      for (int c = 0; c < 4; ++c) {
        float cs = m[c] + m[4+c] + m[8+c] + m[12+c];
        float inv = 1.0f / cs;
        m[c] *= inv; m[4+c] *= inv; m[8+c] *= inv; m[12+c] *= inv;
      }
    }
#pragma unroll
    for (int k = 0; k < 16; ++k) Hres[b * 16 + k] = m[k];
  }
}

// ---------------------------------------------------------------------------
// Kernel 2: x_pre[b,d] = sum_n Hpre[b,n]*x[b,n,d], stored as bf16 (ushort)
// ---------------------------------------------------------------------------
__global__ __launch_bounds__(256) void xpre_kernel(
    const float* __restrict__ x, const float* __restrict__ Hpre,
    unsigned short* __restrict__ xpre)
{
  int b = blockIdx.x, t = threadIdx.x;
  float h0 = Hpre[b*4+0], h1 = Hpre[b*4+1], h2 = Hpre[b*4+2], h3 = Hpre[b*4+3];
  const float4v* xb = (const float4v*)(x + (size_t)b * ND);  // 4 rows of 512 f4
  ushort4v* ob = (ushort4v*)(xpre + (size_t)b * DD);
#pragma unroll
  for (int g = 0; g < 2; ++g) {
    int i = g * 256 + t;                      // float4 index, 0..511
    float4v v = h0 * xb[i] + h1 * xb[512 + i] + h2 * xb[1024 + i] + h3 * xb[1536 + i];
    ushort4v o;
    o.x = f2bf(v.x); o.y = f2bf(v.y); o.z = f2bf(v.z); o.w = f2bf(v.w);
    ob[i] = o;
  }
}

// ---------------------------------------------------------------------------
// Kernel 3: transpose + fp32->bf16 convert: W[K][N] -> Wt[N][K]
// ---------------------------------------------------------------------------
__global__ __launch_bounds__(256) void transpose_bf16_kernel(
    const float* __restrict__ W, unsigned short* __restrict__ Wt, int K, int N)
{
  __shared__ float tile[64][65];
  int tx = threadIdx.x & 63, ty = threadIdx.x >> 6;
  int k0 = blockIdx.y * 64, n0 = blockIdx.x * 64;
#pragma unroll
  for (int r = 0; r < 16; ++r) {
    int kk = r * 4 + ty;
    tile[kk][tx] = W[(size_t)(k0 + kk) * N + n0 + tx];
  }
  __syncthreads();
#pragma unroll
  for (int r = 0; r < 16; ++r) {
    int nn = r * 4 + ty;
    Wt[(size_t)(n0 + nn) * K + k0 + tx] = f2bf(tile[tx][nn]);
  }
}

// ---------------------------------------------------------------------------
// MFMA bf16 GEMM: C[M][N] = A[M][K] @ Bt[N][K]^T  (+bias, epilogue)
// 128x128 block tile, BK=32, 4 waves (2x2), 64x64 per wave, 16x16x32 MFMA.
// EPI=0: fp32 store (+bias). EPI=1: exact gelu -> bf16 store (+bias).
// Layouts per verified m89/m91: A-frag m=lane&15,k=(lane>>4)*8+j;
// B-frag n=lane&15,k=(lane>>4)*8+j; C/D col=lane&15,row=(lane>>4)*4+reg.
// ---------------------------------------------------------------------------
#define GBM 128
#define GBN 128
#define GBK 32
#define LDK 40   // BK + 8 halves pad: 80B row stride, 16B-aligned, 2-way banks

template<int EPI>
__global__ __launch_bounds__(256) void gemm_bf16(
    const unsigned short* __restrict__ A, const unsigned short* __restrict__ Bt,
    const float* __restrict__ bias, void* __restrict__ Cout,
    int M, int N, int K)
{
  __shared__ unsigned short As[GBM * LDK];
  __shared__ unsigned short Bs[GBN * LDK];

  const int t = threadIdx.x;
  const int lane = t & 63, wave = t >> 6;
  const int wm = wave >> 1, wn = wave & 1;
  const int m0 = blockIdx.y * GBM, n0 = blockIdx.x * GBN;

  float4v acc[4][4];
#pragma unroll
  for (int i = 0; i < 4; ++i)
#pragma unroll
    for (int j = 0; j < 4; ++j) acc[i][j] = (float4v)0.0f;

  const int srow = t >> 2;   // 0..63
  const int sgrp = t & 3;    // 0..3  (k-group of 8 halves = 16B)

  for (int kt = 0; kt < K; kt += GBK) {
#pragma unroll
    for (int h = 0; h < 2; ++h) {
      int r = srow + h * 64;
      *(ushort8v*)(&As[r * LDK + sgrp * 8]) =
          *(const ushort8v*)(A + (size_t)(m0 + r) * K + kt + sgrp * 8);
      *(ushort8v*)(&Bs[r * LDK + sgrp * 8]) =
          *(const ushort8v*)(Bt + (size_t)(n0 + r) * K + kt + sgrp * 8);
    }
    __syncthreads();

    const int k0 = (lane >> 4) * 8;
    const int rr = lane & 15;
    bf16x8 af[4], bfr[4];
#pragma unroll
    for (int i = 0; i < 4; ++i) {
      af[i]  = *reinterpret_cast<const bf16x8*>(&As[(wm * 64 + i * 16 + rr) * LDK + k0]);
      bfr[i] = *reinterpret_cast<const bf16x8*>(&Bs[(wn * 64 + i * 16 + rr) * LDK + k0]);
    }
#pragma unroll
    for (int mi = 0; mi < 4; ++mi)
#pragma unroll
      for (int ni = 0; ni < 4; ++ni)
        acc[mi][ni] = __builtin_amdgcn_mfma_f32_16x16x32_bf16(
            af[mi], bfr[ni], acc[mi][ni], 0, 0, 0);
    __syncthreads();
  }

  // epilogue
  const int cl = lane & 15;
  const int rbase = (lane >> 4) * 4;
#pragma unroll
  for (int mi = 0; mi < 4; ++mi) {
#pragma unroll
    for (int ni = 0; ni < 4; ++ni) {
      int col = n0 + wn * 64 + ni * 16 + cl;
      float bv = bias[col];
#pragma unroll
      for (int r = 0; r < 4; ++r) {
        int row = m0 + wm * 64 + mi * 16 + rbase + r;
        float v = acc[mi][ni][r] + bv;
        if (EPI == 1) {
          v = 0.5f * v * (1.0f + erff(v * 0.70710678118654752f));
          ((unsigned short*)Cout)[(size_t)row * N + col] = f2bf(v);
        } else {
          ((float*)Cout)[(size_t)row * N + col] = v;
        }
      }
    }
  }
}

// ---------------------------------------------------------------------------
// Kernel 7: out[b,n,d] = Hpost[b,n]*Hbar[b,d] + sum_m Hres[b,n,m]*x[b,m,d]
// ---------------------------------------------------------------------------
__global__ __launch_bounds__(256) void final_kernel(
    const float* __restrict__ x, const float* __restrict__ Hpost,
    const float* __restrict__ Hres, const float* __restrict__ Hbar,
    float* __restrict__ out)
{
  int b = blockIdx.x, t = threadIdx.x;
  float hp[4], hr[16];
#pragma unroll
  for (int n = 0; n < 4; ++n) hp[n] = Hpost[b * 4 + n];
#pragma unroll
  for (int k = 0; k < 16; ++k) hr[k] = Hres[b * 16 + k];

  const float4v* xb = (const float4v*)(x + (size_t)b * ND);
  const float4v* hb = (const float4v*)(Hbar + (size_t)b * DD);
  float4v* ob = (float4v*)(out + (size_t)b * ND);

#pragma unroll
  for (int g = 0; g < 2; ++g) {
    int i = g * 256 + t;   // float4 index in d, 0..511
    float4v x0 = xb[i], x1 = xb[512 + i], x2 = xb[1024 + i], x3 = xb[1536 + i];
    float4v hv = hb[i];
#pragma unroll
    for (int n = 0; n < 4; ++n) {
      float4v o = hp[n] * hv
                + hr[n*4+0] * x0 + hr[n*4+1] * x1
                + hr[n*4+2] * x2 + hr[n*4+3] * x3;
      ob[n * 512 + i] = o;
    }
  }
}

// ---------------------------------------------------------------------------
extern "C" void kernel_launch(void* const* d_in, const int* in_sizes, int n_in,
                              void* d_out, int out_size, void* d_ws, size_t ws_size,
                              hipStream_t stream) {
  const float* x       = (const float*)d_in[0];
  const float* rms_w   = (const float*)d_in[1];
  const float* th_pre  = (const float*)d_in[2];
  const float* th_post = (const float*)d_in[3];
  const float* th_res  = (const float*)d_in[4];
  const float* a_pre   = (const float*)d_in[5];
  const float* a_post  = (const float*)d_in[6];
  const float* a_res   = (const float*)d_in[7];
  const float* b_pre   = (const float*)d_in[8];
  const float* b_post  = (const float*)d_in[9];
  const float* b_res   = (const float*)d_in[10];
  const float* W1      = (const float*)d_in[11];
  const float* b1      = (const float*)d_in[12];
  const float* W2      = (const float*)d_in[13];
  const float* b2      = (const float*)d_in[14];
  float* out = (float*)d_out;

  char* ws = (char*)d_ws;
  float* Hpre  = (float*)ws;                 ws += (size_t)BB * 4 * 4;
  float* Hpost = (float*)ws;                 ws += (size_t)BB * 4 * 4;
  float* Hres  = (float*)ws;                 ws += (size_t)BB * 16 * 4;
  unsigned short* xpre = (unsigned short*)ws; ws += (size_t)BB * DD * 2;
  unsigned short* W1t  = (unsigned short*)ws; ws += (size_t)DFF * DD * 2;
  unsigned short* W2t  = (unsigned short*)ws; ws += (size_t)DD * DFF * 2;
  unsigned short* G    = (unsigned short*)ws; ws += (size_t)BB * DFF * 2;
  float* Hbar = (float*)ws;                  ws += (size_t)BB * DD * 4;

  row_stats_kernel<<<dim3(BB), dim3(256), 0, stream>>>(
      x, rms_w, th_pre, th_post, th_res, a_pre, a_post, a_res,
      b_pre, b_post, b_res, Hpre, Hpost, Hres);

  xpre_kernel<<<dim3(BB), dim3(256), 0, stream>>>(x, Hpre, xpre);

  // W1[K=DD][N=DFF] -> W1t[DFF][DD]
  transpose_bf16_kernel<<<dim3(DFF / 64, DD / 64), dim3(256), 0, stream>>>(
      W1, W1t, DD, DFF);
  // W2[K=DFF][N=DD] -> W2t[DD][DFF]
  transpose_bf16_kernel<<<dim3(DD / 64, DFF / 64), dim3(256), 0, stream>>>(
      W2, W2t, DFF, DD);

  // GEMM1: G = gelu(xpre @ W1 + b1)   [M=BB, N=DFF, K=DD]
  gemm_bf16<1><<<dim3(DFF / GBN, BB / GBM), dim3(256), 0, stream>>>(
      xpre, W1t, b1, (void*)G, BB, DFF, DD);

  // GEMM2: Hbar = G @ W2 + b2        [M=BB, N=DD, K=DFF]
  gemm_bf16<0><<<dim3(DD / GBN, BB / GBM), dim3(256), 0, stream>>>(
      G, W2t, b2, (void*)Hbar, BB, DD, DFF);

  final_kernel<<<dim3(BB), dim3(256), 0, stream>>>(x, Hpost, Hres, Hbar, out);
}

// Round 2
// 1611.135 us; speedup vs baseline: 1.2685x; 1.2685x over previous
//
#include <hip/hip_runtime.h>
#include <hip/hip_bf16.h>
#include <math.h>

// ---------- types ----------
typedef __attribute__((ext_vector_type(4))) float  float4v;
typedef __attribute__((ext_vector_type(8))) unsigned short ushort8v;
typedef __attribute__((ext_vector_type(4))) unsigned short ushort4v;
typedef __attribute__((ext_vector_type(8))) __bf16 bf16x8;

typedef __attribute__((address_space(3))) unsigned int       lds_u32;
typedef const __attribute__((address_space(1))) unsigned int glb_u32;

#define BB   8192
#define NN   4
#define DD   2048
#define ND   8192   // N*D
#define DFF  8192
#define EPSF 1.1920928955078125e-07f
#define RPB  4      // rows per block in row_stats

__device__ __forceinline__ unsigned short f2bf(float f) {
  union { float f; unsigned int u; } v; v.f = f;
  unsigned int u = v.u;
  u += 0x7FFFu + ((u >> 16) & 1u);   // round-to-nearest-even
  return (unsigned short)(u >> 16);
}

// ---------------------------------------------------------------------------
// Kernel 1: per-row RMS stats + xn@theta_{pre,post,res} + sigmoid + sinkhorn
// RPB rows per block: theta loaded once per element, applied to RPB rows.
// acc[r][0]=sumsq, [1..4]=pre, [5..8]=post, [9..24]=res  (100 VGPRs)
// ---------------------------------------------------------------------------
__global__ __launch_bounds__(256) void row_stats_kernel(
    const float* __restrict__ x, const float* __restrict__ w,
    const float* __restrict__ th_pre, const float* __restrict__ th_post,
    const float* __restrict__ th_res,
    const float* __restrict__ a_pre, const float* __restrict__ a_post,
    const float* __restrict__ a_res,
    const float* __restrict__ b_pre, const float* __restrict__ b_post,
    const float* __restrict__ b_res,
    float* __restrict__ Hpre, float* __restrict__ Hpost, float* __restrict__ Hres)
{
  const int b0 = blockIdx.x * RPB;
  const int t = threadIdx.x;
  const float* xr = x + (size_t)b0 * ND;

  float acc[RPB][25];
#pragma unroll
  for (int r = 0; r < RPB; ++r)
#pragma unroll
    for (int c = 0; c < 25; ++c) acc[r][c] = 0.0f;

  const float4v* tp = (const float4v*)th_pre;   // row i -> tp[i]
  const float4v* tq = (const float4v*)th_post;
  const float4v* tr = (const float4v*)th_res;   // row i -> tr[i*4 .. i*4+3]

  for (int j = 0; j < ND / 256; ++j) {
    int i = j * 256 + t;
    float wv = w[i];
    float4v p  = tp[i];
    float4v q  = tq[i];
    float4v r0 = tr[i*4+0], r1 = tr[i*4+1], r2 = tr[i*4+2], r3 = tr[i*4+3];
#pragma unroll
    for (int r = 0; r < RPB; ++r) {
      float xv = xr[(size_t)r * ND + i];
      float xw = xv * wv;
      acc[r][0] += xv * xv;
      acc[r][1] += xw * p.x;  acc[r][2] += xw * p.y;
      acc[r][3] += xw * p.z;  acc[r][4] += xw * p.w;
      acc[r][5] += xw * q.x;  acc[r][6] += xw * q.y;
      acc[r][7] += xw * q.z;  acc[r][8] += xw * q.w;
      acc[r][9]  += xw * r0.x; acc[r][10] += xw * r0.y;
      acc[r][11] += xw * r0.z; acc[r][12] += xw * r0.w;
      acc[r][13] += xw * r1.x; acc[r][14] += xw * r1.y;
      acc[r][15] += xw * r1.z; acc[r][16] += xw * r1.w;
      acc[r][17] += xw * r2.x; acc[r][18] += xw * r2.y;
      acc[r][19] += xw * r2.z; acc[r][20] += xw * r2.w;
      acc[r][21] += xw * r3.x; acc[r][22] += xw * r3.y;
      acc[r][23] += xw * r3.z; acc[r][24] += xw * r3.w;
    }
  }

  // wave (64-lane) shuffle reduction
#pragma unroll
  for (int r = 0; r < RPB; ++r)
#pragma unroll
    for (int c = 0; c < 25; ++c) {
#pragma unroll
      for (int off = 32; off > 0; off >>= 1)
        acc[r][c] += __shfl_down(acc[r][c], off);
    }

  __shared__ float red[4][RPB * 25];
  __shared__ float s[RPB * 25];
  int lane = t & 63, wv4 = t >> 6;
  if (lane == 0) {
#pragma unroll
    for (int r = 0; r < RPB; ++r)
#pragma unroll
      for (int c = 0; c < 25; ++c) red[wv4][r * 25 + c] = acc[r][c];
  }
  __syncthreads();
  if (t < RPB * 25) s[t] = red[0][t] + red[1][t] + red[2][t] + red[3][t];
  __syncthreads();

  if (t < RPB) {
    const int b = b0 + t;
    const float* sv = &s[t * 25];
    float scale = rsqrtf(sv[0] / (float)ND + EPSF);
    float ap = a_pre[0], apo = a_post[0], ar = a_res[0];

#pragma unroll
    for (int n = 0; n < 4; ++n) {
      float vpre = ap * sv[1 + n] * scale + b_pre[n];
      Hpre[b * 4 + n] = 1.0f / (1.0f + expf(-vpre));
      float vpost = apo * sv[5 + n] * scale + b_post[n];
      Hpost[b * 4 + n] = 2.0f / (1.0f + expf(-vpost));
    }

    float m[16];
#pragma unroll
    for (int k = 0; k < 16; ++k)
      m[k] = expf(ar * sv[9 + k] * scale + b_res[k]);

    for (int it = 0; it < 20; ++it) {
#pragma unroll
      for (int n = 0; n < 4; ++n) {
        float rs = m[n*4] + m[n*4+1] + m[n*4+2] + m[n*4+3];
        float inv = 1.0f / rs;
        m[n*4] *= inv; m[n*4+1] *= inv; m[n*4+2] *= inv; m[n*4+3] *= inv;
      }
#pragma unroll
      for (int c = 0; c < 4; ++c) {
        float cs = m[c] + m[4+c] + m[8+c] + m[12+c];
        float inv = 1.0f / cs;
        m[c] *= inv; m[4+c] *= inv; m[8+c] *= inv; m[12+c] *= inv;
      }
    }
#pragma unroll
    for (int k = 0; k < 16; ++k) Hres[b * 16 + k] = m[k];
  }
}

// ---------------------------------------------------------------------------
// Kernel 2: x_pre[b,d] = sum_n Hpre[b,n]*x[b,n,d], stored as bf16 (ushort)
// ---------------------------------------------------------------------------
__global__ __launch_bounds__(256) void xpre_kernel(
    const float* __restrict__ x, const float* __restrict__ Hpre,
    unsigned short* __restrict__ xpre)
{
  int b = blockIdx.x, t = threadIdx.x;
  float h0 = Hpre[b*4+0], h1 = Hpre[b*4+1], h2 = Hpre[b*4+2], h3 = Hpre[b*4+3];
  const float4v* xb = (const float4v*)(x + (size_t)b * ND);  // 4 rows of 512 f4
  ushort4v* ob = (ushort4v*)(xpre + (size_t)b * DD);
#pragma unroll
  for (int g = 0; g < 2; ++g) {
    int i = g * 256 + t;                      // float4 index, 0..511
    float4v v = h0 * xb[i] + h1 * xb[512 + i] + h2 * xb[1024 + i] + h3 * xb[1536 + i];
    ushort4v o;
    o.x = f2bf(v.x); o.y = f2bf(v.y); o.z = f2bf(v.z); o.w = f2bf(v.w);
    ob[i] = o;
  }
}

// ---------------------------------------------------------------------------
// Kernel 3: transpose + fp32->bf16 convert: W[K][N] -> Wt[N][K]
// ---------------------------------------------------------------------------
__global__ __launch_bounds__(256) void transpose_bf16_kernel(
    const float* __restrict__ W, unsigned short* __restrict__ Wt, int K, int N)
{
  __shared__ float tile[64][65];
  int tx = threadIdx.x & 63, ty = threadIdx.x >> 6;
  int k0 = blockIdx.y * 64, n0 = blockIdx.x * 64;
#pragma unroll
  for (int r = 0; r < 16; ++r) {
    int kk = r * 4 + ty;
    tile[kk][tx] = W[(size_t)(k0 + kk) * N + n0 + tx];
  }
  __syncthreads();
#pragma unroll
  for (int r = 0; r < 16; ++r) {
    int nn = r * 4 + ty;
    Wt[(size_t)(n0 + nn) * K + k0 + tx] = f2bf(tile[tx][nn]);
  }
}

// ---------------------------------------------------------------------------
// MFMA bf16 GEMM (m97 recipe): C[M][N] = A[M][K] @ Bt[N][K]^T (+bias, epilogue)
// 128x128 tile, BK=32, 4 waves (2x2), 64x64/wave, 16x16x32 MFMA.
// Staging via global_load_lds width=16: LDS is UNPADDED [128][32] halves —
// hw scatter = wave-uniform base + lane*16 (m104/m108), so layout must be
// exactly lane-ordered. Wave w stages 16 rows at LDS halves [w*512 (+2048)].
// EPI=0: fp32 store (+bias). EPI=1: exact gelu -> bf16 store (+bias).
// ---------------------------------------------------------------------------
#define GBM 128
#define GBN 128
#define GBK 32

template<int EPI>
__global__ __launch_bounds__(256) void gemm_bf16(
    const unsigned short* __restrict__ A, const unsigned short* __restrict__ Bt,
    const float* __restrict__ bias, void* __restrict__ Cout,
    int M, int N, int K)
{
  __shared__ unsigned short As[GBM * GBK];   // [128][32] halves, no pad
  __shared__ unsigned short Bs[GBN * GBK];

  const int t = threadIdx.x;
  const int lane = t & 63, wave = t >> 6;
  const int wm = wave >> 1, wn = wave & 1;
  const int m0 = blockIdx.y * GBM, n0 = blockIdx.x * GBN;

  float4v acc[4][4];
#pragma unroll
  for (int i = 0; i < 4; ++i)
#pragma unroll
    for (int j = 0; j < 4; ++j) acc[i][j] = (float4v)0.0f;

  // staging addresses: wave w, lane l -> row w*16 + l/4 (+64), k-halves (l&3)*8
  const int srow = wave * 16 + (lane >> 2);
  const int skg  = (lane & 3) * 8;
  const unsigned short* Ag0 = A  + (size_t)(m0 + srow) * K + skg;
  const unsigned short* Ag1 = A  + (size_t)(m0 + srow + 64) * K + skg;
  const unsigned short* Bg0 = Bt + (size_t)(n0 + srow) * K + skg;
  const unsigned short* Bg1 = Bt + (size_t)(n0 + srow + 64) * K + skg;
  // wave-uniform LDS bases (halves)
  unsigned short* Al0 = &As[wave * 512];
  unsigned short* Al1 = &As[2048 + wave * 512];
  unsigned short* Bl0 = &Bs[wave * 512];
  unsigned short* Bl1 = &Bs[2048 + wave * 512];

  const int k0 = (lane >> 4) * 8;
  const int rr = lane & 15;

  for (int kt = 0; kt < K; kt += GBK) {
    __builtin_amdgcn_global_load_lds((glb_u32*)(Ag0 + kt), (lds_u32*)Al0, 16, 0, 0);
    __builtin_amdgcn_global_load_lds((glb_u32*)(Ag1 + kt), (lds_u32*)Al1, 16, 0, 0);
    __builtin_amdgcn_global_load_lds((glb_u32*)(Bg0 + kt), (lds_u32*)Bl0, 16, 0, 0);
    __builtin_amdgcn_global_load_lds((glb_u32*)(Bg1 + kt), (lds_u32*)Bl1, 16, 0, 0);
    __syncthreads();

    bf16x8 af[4], bfr[4];
#pragma unroll
    for (int i = 0; i < 4; ++i) {
      af[i]  = *reinterpret_cast<const bf16x8*>(&As[(wm * 64 + i * 16 + rr) * GBK + k0]);
      bfr[i] = *reinterpret_cast<const bf16x8*>(&Bs[(wn * 64 + i * 16 + rr) * GBK + k0]);
    }
#pragma unroll
    for (int mi = 0; mi < 4; ++mi)
#pragma unroll
      for (int ni = 0; ni < 4; ++ni)
        acc[mi][ni] = __builtin_amdgcn_mfma_f32_16x16x32_bf16(
            af[mi], bfr[ni], acc[mi][ni], 0, 0, 0);
    __syncthreads();
  }

  // epilogue — C/D: col=lane&15, row=(lane>>4)*4+reg (m89/m91 verified)
  const int cl = lane & 15;
  const int rbase = (lane >> 4) * 4;
#pragma unroll
  for (int mi = 0; mi < 4; ++mi) {
#pragma unroll
    for (int ni = 0; ni < 4; ++ni) {
      int col = n0 + wn * 64 + ni * 16 + cl;
      float bv = bias[col];
#pragma unroll
      for (int r = 0; r < 4; ++r) {
        int row = m0 + wm * 64 + mi * 16 + rbase + r;
        float v = acc[mi][ni][r] + bv;
        if (EPI == 1) {
          v = 0.5f * v * (1.0f + erff(v * 0.70710678118654752f));
          ((unsigned short*)Cout)[(size_t)row * N + col] = f2bf(v);
        } else {
          ((float*)Cout)[(size_t)row * N + col] = v;
        }
      }
    }
  }
}

// ---------------------------------------------------------------------------
// Kernel 7: out[b,n,d] = Hpost[b,n]*Hbar[b,d] + sum_m Hres[b,n,m]*x[b,m,d]
// ---------------------------------------------------------------------------
__global__ __launch_bounds__(256) void final_kernel(
    const float* __restrict__ x, const float* __restrict__ Hpost,
    const float* __restrict__ Hres, const float* __restrict__ Hbar,
    float* __restrict__ out)
{
  int b = blockIdx.x, t = threadIdx.x;
  float hp[4], hr[16];
#pragma unroll
  for (int n = 0; n < 4; ++n) hp[n] = Hpost[b * 4 + n];
#pragma unroll
  for (int k = 0; k < 16; ++k) hr[k] = Hres[b * 16 + k];

  const float4v* xb = (const float4v*)(x + (size_t)b * ND);
  const float4v* hb = (const float4v*)(Hbar + (size_t)b * DD);
  float4v* ob = (float4v*)(out + (size_t)b * ND);

#pragma unroll
  for (int g = 0; g < 2; ++g) {
    int i = g * 256 + t;   // float4 index in d, 0..511
    float4v x0 = xb[i], x1 = xb[512 + i], x2 = xb[1024 + i], x3 = xb[1536 + i];
    float4v hv = hb[i];
#pragma unroll
    for (int n = 0; n < 4; ++n) {
      float4v o = hp[n] * hv
                + hr[n*4+0] * x0 + hr[n*4+1] * x1
                + hr[n*4+2] * x2 + hr[n*4+3] * x3;
      ob[n * 512 + i] = o;
    }
  }
}

// ---------------------------------------------------------------------------
extern "C" void kernel_launch(void* const* d_in, const int* in_sizes, int n_in,
                              void* d_out, int out_size, void* d_ws, size_t ws_size,
                              hipStream_t stream) {
  const float* x       = (const float*)d_in[0];
  const float* rms_w   = (const float*)d_in[1];
  const float* th_pre  = (const float*)d_in[2];
  const float* th_post = (const float*)d_in[3];
  const float* th_res  = (const float*)d_in[4];
  const float* a_pre   = (const float*)d_in[5];
  const float* a_post  = (const float*)d_in[6];
  const float* a_res   = (const float*)d_in[7];
  const float* b_pre   = (const float*)d_in[8];
  const float* b_post  = (const float*)d_in[9];
  const float* b_res   = (const float*)d_in[10];
  const float* W1      = (const float*)d_in[11];
  const float* b1      = (const float*)d_in[12];
  const float* W2      = (const float*)d_in[13];
  const float* b2      = (const float*)d_in[14];
  float* out = (float*)d_out;

  char* ws = (char*)d_ws;
  float* Hpre  = (float*)ws;                 ws += (size_t)BB * 4 * 4;
  float* Hpost = (float*)ws;                 ws += (size_t)BB * 4 * 4;
  float* Hres  = (float*)ws;                 ws += (size_t)BB * 16 * 4;
  unsigned short* xpre = (unsigned short*)ws; ws += (size_t)BB * DD * 2;
  unsigned short* W1t  = (unsigned short*)ws; ws += (size_t)DFF * DD * 2;
  unsigned short* W2t  = (unsigned short*)ws; ws += (size_t)DD * DFF * 2;
  unsigned short* G    = (unsigned short*)ws; ws += (size_t)BB * DFF * 2;
  float* Hbar = (float*)ws;                  ws += (size_t)BB * DD * 4;

  row_stats_kernel<<<dim3(BB / RPB), dim3(256), 0, stream>>>(
      x, rms_w, th_pre, th_post, th_res, a_pre, a_post, a_res,
      b_pre, b_post, b_res, Hpre, Hpost, Hres);

  xpre_kernel<<<dim3(BB), dim3(256), 0, stream>>>(x, Hpre, xpre);

  // W1[K=DD][N=DFF] -> W1t[DFF][DD]
  transpose_bf16_kernel<<<dim3(DFF / 64, DD / 64), dim3(256), 0, stream>>>(
      W1, W1t, DD, DFF);
  // W2[K=DFF][N=DD] -> W2t[DD][DFF]
  transpose_bf16_kernel<<<dim3(DD / 64, DFF / 64), dim3(256), 0, stream>>>(
      W2, W2t, DFF, DD);

  // GEMM1: G = gelu(xpre @ W1 + b1)   [M=BB, N=DFF, K=DD]
  gemm_bf16<1><<<dim3(DFF / GBN, BB / GBM), dim3(256), 0, stream>>>(
      xpre, W1t, b1, (void*)G, BB, DFF, DD);

  // GEMM2: Hbar = G @ W2 + b2        [M=BB, N=DD, K=DFF]
  gemm_bf16<0><<<dim3(DD / GBN, BB / GBM), dim3(256), 0, stream>>>(
      G, W2t, b2, (void*)Hbar, BB, DD, DFF);

  final_kernel<<<dim3(BB), dim3(256), 0, stream>>>(x, Hpost, Hres, Hbar, out);
}